// Round 1
// baseline (3300.092 us; speedup 1.0000x reference)
//
#include <hip/hip_runtime.h>
#include <math.h>

#define S_ 4
#define L_ 2048
#define D_ 1024
#define H_ 16
#define DH_ 64
#define TTOT_ 8192
#define WCL_ 384
#define KMAX_ 16
#define MAXCL_ (S_*KMAX_)
#define MAXLEN_ (WCL_+1)   // 385
#define LSCAP_ 4096
#define NELEM_ ((size_t)TTOT_*(size_t)D_)

// ---------------------------------------------------------------------------
// GEMM: C[M,N] = A[M,K] * B[N,K]^T   (both row-major, contraction over 2nd idx)
// 64x64 tile, 256 threads, 4x4 micro-tile, K-chunk 16.
// ---------------------------------------------------------------------------
__global__ __launch_bounds__(256)
void gemm_nt(const float* __restrict__ A, const float* __restrict__ B,
             float* __restrict__ C, int M, int N, int Kd) {
  __shared__ float As[16][68];
  __shared__ float Bs[16][68];
  const int tx = threadIdx.x & 15, ty = threadIdx.x >> 4;
  const int m0 = blockIdx.x * 64, n0 = blockIdx.y * 64;
  const int lr = threadIdx.x >> 2, lc = threadIdx.x & 3;
  float acc[4][4] = {};
  for (int k0 = 0; k0 < Kd; k0 += 16) {
    __syncthreads();
    float4 a4 = *(const float4*)(A + (size_t)(m0 + lr) * Kd + k0 + lc * 4);
    float4 b4 = *(const float4*)(B + (size_t)(n0 + lr) * Kd + k0 + lc * 4);
    As[lc*4+0][lr] = a4.x; As[lc*4+1][lr] = a4.y; As[lc*4+2][lr] = a4.z; As[lc*4+3][lr] = a4.w;
    Bs[lc*4+0][lr] = b4.x; Bs[lc*4+1][lr] = b4.y; Bs[lc*4+2][lr] = b4.z; Bs[lc*4+3][lr] = b4.w;
    __syncthreads();
#pragma unroll
    for (int kk = 0; kk < 16; kk++) {
      float4 av = *(const float4*)&As[kk][ty * 4];
      float4 bv = *(const float4*)&Bs[kk][tx * 4];
      float aa[4] = {av.x, av.y, av.z, av.w};
      float bb[4] = {bv.x, bv.y, bv.z, bv.w};
#pragma unroll
      for (int i = 0; i < 4; i++)
#pragma unroll
        for (int j = 0; j < 4; j++) acc[i][j] += aa[i] * bb[j];
    }
  }
#pragma unroll
  for (int i = 0; i < 4; i++)
#pragma unroll
    for (int j = 0; j < 4; j++)
      C[(size_t)(m0 + ty * 4 + i) * N + (n0 + tx * 4 + j)] = acc[i][j];
}

// ---------------------------------------------------------------------------
// Routing features: r = 0.5*(l2n(mean_h qh) + l2n(mean_h kh)), one wave/token.
// ---------------------------------------------------------------------------
__global__ __launch_bounds__(256)
void feats_kernel(const float* __restrict__ Q, const float* __restrict__ K,
                  float* __restrict__ FE) {
  int t = blockIdx.x * 4 + (threadIdx.x >> 6);
  int lane = threadIdx.x & 63;
  if (t >= TTOT_) return;
  float qm = 0.f, km = 0.f;
#pragma unroll
  for (int h = 0; h < H_; h++) {
    qm += Q[(size_t)t * D_ + h * DH_ + lane];
    km += K[(size_t)t * D_ + h * DH_ + lane];
  }
  qm *= (1.0f / 16.0f);
  km *= (1.0f / 16.0f);
  float q2 = qm * qm, k2 = km * km;
#pragma unroll
  for (int m = 1; m < 64; m <<= 1) {
    q2 += __shfl_xor(q2, m, 64);
    k2 += __shfl_xor(k2, m, 64);
  }
  float r = 0.5f * (qm / (sqrtf(q2) + 1e-6f) + km / (sqrtf(k2) + 1e-6f));
  FE[(size_t)t * DH_ + lane] = r;
}

// ---------------------------------------------------------------------------
// Routing: 1 block per sequence, replicates _route_np exactly.
// ---------------------------------------------------------------------------
__device__ __forceinline__ float dot64(const float* __restrict__ f,
                                       const float* __restrict__ c) {
  float s = 0.f;
#pragma unroll
  for (int c4 = 0; c4 < 16; c4++) {
    float4 fv = *(const float4*)(f + c4 * 4);
    float4 cv = *(const float4*)(c + c4 * 4);
    s += fv.x * cv.x; s += fv.y * cv.y; s += fv.z * cv.z; s += fv.w * cv.w;
  }
  return s;
}

__global__ __launch_bounds__(1024)
void routing_kernel(const float* __restrict__ FE, const int* __restrict__ seqlens,
                    const int* __restrict__ gidx, int* __restrict__ cT,
                    int* __restrict__ cL, int* __restrict__ tC) {
  __shared__ float cent[KMAX_][64];
  __shared__ float csum[KMAX_][64];
  __shared__ int cnt1[KMAX_];
  __shared__ int cnt2[KMAX_];
  __shared__ int starts[KMAX_ + 1];
  __shared__ unsigned char assign[LSCAP_];
  __shared__ unsigned long long keys[LSCAP_];

  const int s = blockIdx.x, tid = threadIdx.x;
  int a = 0;
  for (int t = 0; t < s; t++) a += seqlens[t];
  int Ls = seqlens[s];
  if (Ls > LSCAP_) Ls = LSCAP_;
  for (int cs = tid; cs < KMAX_; cs += 1024) cL[s * KMAX_ + cs] = 0;
  if (Ls <= 0) return;

  int wloc = Ls < WCL_ ? Ls : WCL_;
  if (wloc < 1) wloc = 1;
  int k = (Ls + wloc - 1) / wloc;
  if (k < 1) k = 1;
  if (k > KMAX_) k = KMAX_;

  // centroid init: feats at round(linspace(0, Ls-1, k))  (double, half-even)
  if (tid < k * 64) {
    int j = tid >> 6, d = tid & 63;
    double step = (k > 1) ? (double)(Ls - 1) / (double)(k - 1) : 0.0;
    long ii = (long)rint(step * (double)j);
    if (ii < 0) ii = 0;
    if (ii > Ls - 1) ii = Ls - 1;
    cent[j][d] = FE[(size_t)(a + ii) * DH_ + d];
  }
  if (tid < KMAX_) cnt1[tid] = 0;
  __syncthreads();

  // ---- one k-means iteration (ROUTING_ITERS = 1) ----
  for (int i = tid; i < Ls; i += 1024) {
    const float* f = FE + (size_t)(a + i) * DH_;
    float best = -1e30f; int bj = 0;
    for (int j = 0; j < k; j++) {
      float sd = dot64(f, &cent[j][0]);
      if (sd > best) { best = sd; bj = j; }      // first-max tie-break
    }
    assign[i] = (unsigned char)bj;
  }
  __syncthreads();
  for (int i = tid; i < Ls; i += 1024) atomicAdd(&cnt1[assign[i]], 1);
  __syncthreads();
  // deterministic per-dim sequential scatter-sum (matches np.add.at order)
  if (tid < 64) {
    int d = tid;
    for (int j = 0; j < k; j++) csum[j][d] = 0.f;
    for (int i = 0; i < Ls; i++)
      csum[assign[i]][d] += FE[(size_t)(a + i) * DH_ + d];
  }
  __syncthreads();
  if (tid < k * 64) {
    int j = tid >> 6, d = tid & 63;
    float v = csum[j][d] / fmaxf((float)cnt1[j], 1.0f);
    float sq = v * v;
#pragma unroll
    for (int m = 1; m < 64; m <<= 1) sq += __shfl_xor(sq, m, 64);
    cent[j][d] = v / (sqrtf(sq) + 1e-6f);
  }
  __syncthreads();

  // ---- final assign + own + composite sort keys ----
  int NP2 = 1;
  while (NP2 < Ls) NP2 <<= 1;
  for (int i = tid; i < NP2; i += 1024) {
    unsigned long long key;
    if (i < Ls) {
      const float* f = FE + (size_t)(a + i) * DH_;
      float best = -1e30f; int bj = 0;
      for (int j = 0; j < k; j++) {
        float sd = dot64(f, &cent[j][0]);
        if (sd > best) { best = sd; bj = j; }
      }
      assign[i] = (unsigned char)bj;
      unsigned int u = __float_as_uint(best);
      unsigned int ord = (u & 0x80000000u) ? ~u : (u | 0x80000000u); // asc map
      unsigned int dsc = ~ord;                                      // descending own
      key = ((unsigned long long)bj << 45) |
            ((unsigned long long)dsc << 13) | (unsigned long long)i;
    } else {
      key = ~0ull;
    }
    keys[i] = key;
  }
  if (tid < KMAX_) cnt2[tid] = 0;
  __syncthreads();
  for (int i = tid; i < Ls; i += 1024) atomicAdd(&cnt2[assign[i]], 1);
  __syncthreads();

  // ---- bitonic sort ascending: (cid asc, own desc, idx asc) ----
  for (int len2 = 2; len2 <= NP2; len2 <<= 1) {
    for (int st = len2 >> 1; st > 0; st >>= 1) {
      for (int i = tid; i < NP2; i += 1024) {
        int j = i ^ st;
        if (j > i) {
          unsigned long long x = keys[i], y = keys[j];
          bool asc = ((i & len2) == 0);
          if ((x > y) == asc) { keys[i] = y; keys[j] = x; }
        }
      }
      __syncthreads();
    }
  }
  if (tid == 0) {
    starts[0] = 0;
    for (int j = 0; j < k; j++) starts[j + 1] = starts[j] + cnt2[j];
  }
  __syncthreads();

  // ---- emit clusters: top-min(count,wloc) per cluster + global token ----
  const int g = gidx[s];
  int cOut = 0;
  for (int j = 0; j < k; j++) {
    int cj = cnt2[j];
    if (cj <= 0) continue;
    int keep = cj < wloc ? cj : wloc;
    int slot = s * KMAX_ + cOut;
    for (int p = tid; p < keep; p += 1024) {
      int token = a + (int)(keys[starts[j] + p] & 0x1FFFull);
      cT[slot * MAXLEN_ + p] = token;
      atomicAdd(&tC[token], 1);
    }
    if (tid == 0) {
      cT[slot * MAXLEN_ + keep] = g;
      atomicAdd(&tC[g], 1);
      cL[slot] = keep + 1;
    }
    cOut++;
  }
}

// ---------------------------------------------------------------------------
// Per-cluster-per-head flash attention. 512 thr (8 waves), 2 q-rows/wave/pass,
// 64-key K/V tiles in LDS with chunk-XOR swizzle (bank-conflict-free reads).
// ---------------------------------------------------------------------------
__global__ __launch_bounds__(512)
void attn_kernel(const float* __restrict__ Q, const float* __restrict__ K,
                 const float* __restrict__ V, const int* __restrict__ cT,
                 const int* __restrict__ cL, float* __restrict__ OH) {
  const int c = blockIdx.x, h = blockIdx.y;
  const int len = cL[c];
  if (len <= 0) return;

  __shared__ int toks[MAXLEN_];
  __shared__ float Ks[64][64];
  __shared__ float Vs[64][64];
  __shared__ float qs[16][64];
  __shared__ float ps[8][2][64];

  const int tid = threadIdx.x, wave = tid >> 6, lane = tid & 63;
  for (int i = tid; i < len; i += 512) toks[i] = cT[c * MAXLEN_ + i];
  __syncthreads();

  const int ntile = (len + 63) >> 6;
  const int npass = (len + 15) >> 4;
  for (int pass = 0; pass < npass; pass++) {
    __syncthreads();  // protect qs from previous pass readers
    for (int e = tid; e < 1024; e += 512) {
      int lrr = e >> 6, d = e & 63;
      int row = pass * 16 + lrr;
      qs[lrr][d] = (row < len) ? Q[(size_t)toks[row] * D_ + h * DH_ + d] : 0.f;
    }
    const int lr0 = wave * 2, lr1 = wave * 2 + 1;
    const int row0 = pass * 16 + lr0, row1 = pass * 16 + lr1;
    float acc0 = 0.f, acc1 = 0.f, mm0 = -INFINITY, mm1 = -INFINITY;
    float ll0 = 0.f, ll1 = 0.f;

    for (int mt = 0; mt < ntile; mt++) {
      __syncthreads();
      // stage K,V tile (zero-fill invalid rows), swizzled chunk layout
      for (int e = tid; e < 2048; e += 512) {
        int mat = e >> 10;
        int idx = e & 1023;
        int rr = idx >> 4, c4 = idx & 15;
        int mg = mt * 64 + rr;
        float4 v4 = make_float4(0.f, 0.f, 0.f, 0.f);
        if (mg < len) {
          const float* src = (mat ? V : K) + (size_t)toks[mg] * D_ + h * DH_ + c4 * 4;
          v4 = *(const float4*)src;
        }
        int sc = (c4 ^ (rr & 15)) * 4;
        float* dst = mat ? &Vs[rr][sc] : &Ks[rr][sc];
        *(float4*)dst = v4;
      }
      __syncthreads();

      // scores: lane <-> key (mt*64 + lane)
      int mg = mt * 64 + lane;
      float s0, s1;
      if (mg < len) {
        float d0 = 0.f, d1 = 0.f;
#pragma unroll
        for (int c4 = 0; c4 < 16; c4++) {
          float4 kv = *(const float4*)&Ks[lane][(c4 ^ (lane & 15)) * 4];
          float4 q0 = *(const float4*)&qs[lr0][c4 * 4];
          float4 q1 = *(const float4*)&qs[lr1][c4 * 4];
          d0 += q0.x * kv.x; d0 += q0.y * kv.y; d0 += q0.z * kv.z; d0 += q0.w * kv.w;
          d1 += q1.x * kv.x; d1 += q1.y * kv.y; d1 += q1.z * kv.z; d1 += q1.w * kv.w;
        }
        s0 = d0 * 0.125f; s1 = d1 * 0.125f;
      } else {
        s0 = -INFINITY; s1 = -INFINITY;
      }
      float t0 = s0, t1 = s1;
#pragma unroll
      for (int m = 1; m < 64; m <<= 1) {
        t0 = fmaxf(t0, __shfl_xor(t0, m, 64));
        t1 = fmaxf(t1, __shfl_xor(t1, m, 64));
      }
      float n0 = fmaxf(mm0, t0), n1 = fmaxf(mm1, t1);
      float cor0 = expf(mm0 - n0), cor1 = expf(mm1 - n1);
      float p0 = expf(s0 - n0), p1 = expf(s1 - n1);
      float sum0 = p0, sum1 = p1;
#pragma unroll
      for (int m = 1; m < 64; m <<= 1) {
        sum0 += __shfl_xor(sum0, m, 64);
        sum1 += __shfl_xor(sum1, m, 64);
      }
      ll0 = ll0 * cor0 + sum0;
      ll1 = ll1 * cor1 + sum1;
      acc0 *= cor0; acc1 *= cor1;
      mm0 = n0; mm1 = n1;
      ps[wave][0][lane] = p0;
      ps[wave][1][lane] = p1;
      // PV: lane <-> output dim d; V read swizzle-permuted (conflict-free)
#pragma unroll
      for (int mq = 0; mq < 16; mq++) {
        float4 pv0 = *(const float4*)&ps[wave][0][mq * 4];
        float4 pv1 = *(const float4*)&ps[wave][1][mq * 4];
        float pa0[4] = {pv0.x, pv0.y, pv0.z, pv0.w};
        float pa1[4] = {pv1.x, pv1.y, pv1.z, pv1.w};
#pragma unroll
        for (int u = 0; u < 4; u++) {
          int ml = mq * 4 + u;
          float v = Vs[ml][((lane >> 2) ^ (ml & 15)) * 4 + (lane & 3)];
          acc0 += pa0[u] * v;
          acc1 += pa1[u] * v;
        }
      }
    }
    if (row0 < len)
      atomicAdd(&OH[(size_t)toks[row0] * D_ + h * DH_ + lane], acc0 / ll0);
    if (row1 < len)
      atomicAdd(&OH[(size_t)toks[row1] * D_ + h * DH_ + lane], acc1 / ll1);
  }
}

// ---------------------------------------------------------------------------
// out_h /= clip(cnt, 1)
// ---------------------------------------------------------------------------
__global__ __launch_bounds__(256)
void norm_oh(float* __restrict__ OH, const int* __restrict__ cnt) {
  size_t i = (size_t)blockIdx.x * 256 + threadIdx.x;  // float4 index
  size_t n4 = NELEM_ / 4;
  if (i >= n4) return;
  int row = (int)((i * 4) >> 10);
  int cc = cnt[row];
  float s = 1.0f / (float)(cc > 1 ? cc : 1);
  float4* p = (float4*)OH + i;
  float4 v = *p;
  v.x *= s; v.y *= s; v.z *= s; v.w *= s;
  *p = v;
}

// ---------------------------------------------------------------------------
extern "C" void kernel_launch(void* const* d_in, const int* in_sizes, int n_in,
                              void* d_out, int out_size, void* d_ws, size_t ws_size,
                              hipStream_t stream) {
  (void)in_sizes; (void)n_in; (void)out_size; (void)ws_size;
  const float* q_in = (const float*)d_in[0];
  const float* k_in = (const float*)d_in[1];
  const float* v_in = (const float*)d_in[2];
  const int* seqlens = (const int*)d_in[3];
  const int* gidx    = (const int*)d_in[4];
  const float* Wq = (const float*)d_in[5];
  const float* Wk = (const float*)d_in[6];
  const float* Wv = (const float*)d_in[7];
  const float* Wo = (const float*)d_in[8];
  float* out = (float*)d_out;

  float* Q  = (float*)d_ws;
  float* K  = Q + NELEM_;
  float* V  = K + NELEM_;
  float* OH = V + NELEM_;
  float* FE = OH + NELEM_;
  int* cT = (int*)(FE + (size_t)TTOT_ * DH_);
  int* cL = cT + MAXCL_ * MAXLEN_;
  int* tC = cL + MAXCL_;

  hipMemsetAsync(OH, 0, NELEM_ * sizeof(float), stream);
  hipMemsetAsync(tC, 0, TTOT_ * sizeof(int), stream);

  dim3 gg(TTOT_ / 64, D_ / 64);
  gemm_nt<<<gg, 256, 0, stream>>>(q_in, Wq, Q, TTOT_, D_, D_);
  gemm_nt<<<gg, 256, 0, stream>>>(k_in, Wk, K, TTOT_, D_, D_);
  gemm_nt<<<gg, 256, 0, stream>>>(v_in, Wv, V, TTOT_, D_, D_);
  feats_kernel<<<TTOT_ / 4, 256, 0, stream>>>(Q, K, FE);
  routing_kernel<<<S_, 1024, 0, stream>>>(FE, seqlens, gidx, cT, cL, tC);
  attn_kernel<<<dim3(MAXCL_, H_), 512, 0, stream>>>(Q, K, V, cT, cL, OH);
  norm_oh<<<(unsigned)((NELEM_ / 4 + 255) / 256), 256, 0, stream>>>(OH, tC);
  gemm_nt<<<gg, 256, 0, stream>>>(OH, Wo, out, TTOT_, D_, D_);
}